// Round 4
// baseline (2000.799 us; speedup 1.0000x reference)
//
#include <hip/hip_runtime.h>
#include <cstdint>
#include <cstddef>

#define T_LEN   4096
#define B_SZ    32
#define H_DIM   128
#define DX      128
#define K_CLS   10
#define CHUNK   32
#define NCHUNKS (T_LEN / CHUNK)
#define XA_LD   136   // f16 per xA row
#define XP_LD   520   // f16 per xPL row: 128 units * 4 (r,z,n,pad) + 8 pad
#define HI_LD   136

typedef _Float16 half2v  __attribute__((ext_vector_type(2)));
typedef _Float16 half4   __attribute__((ext_vector_type(4)));
typedef _Float16 half8   __attribute__((ext_vector_type(8)));
typedef float    floatx4 __attribute__((ext_vector_type(4)));

// Raw barrier: orders LDS ops only (no vmcnt drain).
#define LGKM_BARRIER() do {                                   \
    asm volatile("s_waitcnt lgkmcnt(0)" ::: "memory");        \
    __builtin_amdgcn_s_barrier();                             \
    asm volatile("" ::: "memory");                            \
  } while (0)

__global__ void __launch_bounds__(256) init_out_kernel(float* __restrict__ out,
                                                       const float* __restrict__ bfc) {
  int i = blockIdx.x * 256 + threadIdx.x;
  if (i < B_SZ * T_LEN * K_CLS) out[i] = bfc[i % K_CLS];
}

// One block per (batch, direction) scan. 4 waves (256 threads, 1 wave/SIMD):
//  - each wave owns 32 hidden units (2 col-tiles x 3 gates = 24 MFMA/step)
//  - hp = Whh @ h via MFMA, all A-rows = broadcast h; Whh+Wih stationary in
//    VGPRs (192); weights pre-scaled by log2e (r,z) / 2log2e (n) -> raw v_exp2
//  - 4-wave barrier convoy + halved LDS burst vs the 8-wave version
__global__ void __launch_bounds__(256, 1)
gru_bidir_kernel(const float* __restrict__ x,
                 const float* __restrict__ Wih_f, const float* __restrict__ Whh_f,
                 const float* __restrict__ bih_f, const float* __restrict__ bhh_f,
                 const float* __restrict__ Wih_b, const float* __restrict__ Whh_b,
                 const float* __restrict__ bih_b, const float* __restrict__ bhh_b,
                 const float* __restrict__ Wfc, float* __restrict__ out) {
  const int tid = threadIdx.x;
  const int bid = blockIdx.x;
  const int b   = bid & (B_SZ - 1);
  const int dir = bid >> 5;

  const float* Wih = dir ? Wih_b : Wih_f;
  const float* Whh = dir ? Whh_b : Whh_f;
  const float* bih = dir ? bih_b : bih_f;
  const float* bhh = dir ? bhh_b : bhh_f;

  const int lane = tid & 63;
  const int wv   = tid >> 6;      // 0..3
  const int col  = lane & 15;
  const int quad = lane >> 4;
  const int j0   = wv * 32 + col;        // unit for col-tile 0
  const int j1   = j0 + 16;              // unit for col-tile 1

  __shared__ __align__(16) _Float16 xA[CHUNK][XA_LD];
  __shared__ __align__(16) _Float16 xPL[CHUNK][XP_LD];
  __shared__ __align__(16) _Float16 hist[CHUNK + 1][HI_LD];

  const float LOG2E = 1.44269504f;

  // ---- stationary weight fragments [ct][g][kt], pre-scaled for exp2 gates ----
  half8 whf[2][3][4];   // 96 VGPR
  half8 wif[2][3][4];   // 96 VGPR
#pragma unroll
  for (int ct = 0; ct < 2; ++ct) {
    const int jct = wv * 32 + ct * 16 + col;
#pragma unroll
    for (int g = 0; g < 3; ++g) {
      const float gs = (g == 2) ? 2.0f * LOG2E : LOG2E;
#pragma unroll
      for (int kt = 0; kt < 4; ++kt) {
        const float* sh = Whh + (size_t)(g * H_DIM + jct) * H_DIM + kt * 32 + quad * 8;
        const float* si = Wih + (size_t)(g * H_DIM + jct) * DX + kt * 32 + quad * 8;
        half8 vh, vi;
#pragma unroll
        for (int e = 0; e < 8; ++e) {
          vh[e] = (_Float16)(sh[e] * gs);
          vi[e] = (_Float16)(si[e] * gs);
        }
        whf[ct][g][kt] = vh;
        wif[ct][g][kt] = vi;
      }
    }
  }
  float br[2], bz[2], bn[2];
  floatx4 cNbv[2];
#pragma unroll
  for (int ct = 0; ct < 2; ++ct) {
    const int jct = wv * 32 + ct * 16 + col;
    br[ct] = (bih[jct] + bhh[jct]) * LOG2E;
    bz[ct] = (bih[H_DIM + jct] + bhh[H_DIM + jct]) * LOG2E;
    bn[ct] = bih[2 * H_DIM + jct] * (2.0f * LOG2E);
    float bh = bhh[2 * H_DIM + jct] * (2.0f * LOG2E);
    cNbv[ct] = (floatx4){bh, bh, bh, bh};
  }

  // ---- Wfc fragments for fused FC (waves 0..1) ----
  half8 fcf[4];
  if (wv < 2) {
#pragma unroll
    for (int kt = 0; kt < 4; ++kt) {
      half8 v;
#pragma unroll
      for (int e = 0; e < 8; ++e) {
        int k = kt * 32 + quad * 8 + e;
        v[e] = (col < K_CLS) ? (_Float16)Wfc[(size_t)col * (2 * H_DIM) + dir * H_DIM + k]
                             : (_Float16)0.f;
      }
      fcf[kt] = v;
    }
  }

  if (tid < H_DIM) hist[0][tid] = (_Float16)0.f;

  // ---- x prefetch: thread covers row s_row, 16 consecutive floats ----
  const int s_row = tid >> 3;        // 0..31
  const int cb    = (tid & 7) * 16;  // 0..112
  float4 px0, px1, px2, px3;
  {
    int t0 = dir ? (T_LEN - 1 - s_row) : s_row;
    const float* xr = x + ((size_t)b * T_LEN + t0) * DX + cb;
    px0 = *(const float4*)xr;        px1 = *(const float4*)(xr + 4);
    px2 = *(const float4*)(xr + 8);  px3 = *(const float4*)(xr + 12);
  }

  float hold0 = 0.f, hold1 = 0.f;
  const floatx4 z4 = {0.f, 0.f, 0.f, 0.f};
  __syncthreads();

  for (int c = 0; c < NCHUNKS; ++c) {
    // ---- stage x chunk into LDS (f16) ----
    {
      half8 lo, hi;
      lo[0] = (_Float16)px0.x; lo[1] = (_Float16)px0.y; lo[2] = (_Float16)px0.z; lo[3] = (_Float16)px0.w;
      lo[4] = (_Float16)px1.x; lo[5] = (_Float16)px1.y; lo[6] = (_Float16)px1.z; lo[7] = (_Float16)px1.w;
      hi[0] = (_Float16)px2.x; hi[1] = (_Float16)px2.y; hi[2] = (_Float16)px2.z; hi[3] = (_Float16)px2.w;
      hi[4] = (_Float16)px3.x; hi[5] = (_Float16)px3.y; hi[6] = (_Float16)px3.z; hi[7] = (_Float16)px3.w;
      *(half8*)&xA[s_row][cb] = lo;
      *(half8*)&xA[s_row][cb + 8] = hi;
    }
    LGKM_BARRIER();

    // ---- xp = (x @ Wih^T + bias), pre-scaled, packed [row][j*4+g] ----
#pragma unroll
    for (int mt = 0; mt < 2; ++mt) {
      half8 af[4];
#pragma unroll
      for (int kt = 0; kt < 4; ++kt)
        af[kt] = *(const half8*)&xA[mt * 16 + col][kt * 32 + quad * 8];
#pragma unroll
      for (int ct = 0; ct < 2; ++ct) {
        floatx4 pr = z4, pz = z4, pn = z4;
#pragma unroll
        for (int kt = 0; kt < 4; ++kt) {
          pr = __builtin_amdgcn_mfma_f32_16x16x32_f16(af[kt], wif[ct][0][kt], pr, 0, 0, 0);
          pz = __builtin_amdgcn_mfma_f32_16x16x32_f16(af[kt], wif[ct][1][kt], pz, 0, 0, 0);
          pn = __builtin_amdgcn_mfma_f32_16x16x32_f16(af[kt], wif[ct][2][kt], pn, 0, 0, 0);
        }
        const int jw = (ct ? j1 : j0) * 4;
#pragma unroll
        for (int i = 0; i < 4; ++i) {
          half4 w;
          w[0] = (_Float16)(pr[i] + br[ct]);
          w[1] = (_Float16)(pz[i] + bz[ct]);
          w[2] = (_Float16)(pn[i] + bn[ct]);
          w[3] = (_Float16)0.f;
          *(half4*)&xPL[mt * 16 + quad * 4 + i][jw] = w;
        }
      }
    }

    // prefetch next chunk's x (stays in flight across the scan)
    if (c + 1 < NCHUNKS) {
      int s  = (c + 1) * CHUNK + s_row;
      int t0 = dir ? (T_LEN - 1 - s) : s;
      const float* xr = x + ((size_t)b * T_LEN + t0) * DX + cb;
      px0 = *(const float4*)xr;        px1 = *(const float4*)(xr + 4);
      px2 = *(const float4*)(xr + 8);  px3 = *(const float4*)(xr + 12);
    }
    LGKM_BARRIER();

    uint2 xv0 = *(const uint2*)&xPL[0][j0 * 4];
    uint2 xv1 = *(const uint2*)&xPL[0][j1 * 4];

    // ---- sequential scan (fully unrolled: immediate LDS offsets) ----
#pragma unroll
    for (int s = 0; s < CHUNK; ++s) {
      // broadcast h fragments: address depends only on quad -> every A-row = h
      half8 haf[4];
#pragma unroll
      for (int kt = 0; kt < 4; ++kt)
        haf[kt] = *(const half8*)&hist[s][kt * 32 + quad * 8];
      uint2 xvn0 = *(const uint2*)&xPL[(s + 1) & (CHUNK - 1)][j0 * 4];
      uint2 xvn1 = *(const uint2*)&xPL[(s + 1) & (CHUNK - 1)][j1 * 4];

      half2v xa0 = __builtin_bit_cast(half2v, xv0.x);
      half2v xb0 = __builtin_bit_cast(half2v, xv0.y);
      half2v xa1 = __builtin_bit_cast(half2v, xv1.x);
      half2v xb1 = __builtin_bit_cast(half2v, xv1.y);
      float xr0 = (float)xa0.x, xz0 = (float)xa0.y, xn0 = (float)xb0.x;
      float xr1 = (float)xa1.x, xz1 = (float)xa1.y, xn1 = (float)xb1.x;
      floatx4 cR0 = {xr0, xr0, xr0, xr0}, cZ0 = {xz0, xz0, xz0, xz0};
      floatx4 cR1 = {xr1, xr1, xr1, xr1}, cZ1 = {xz1, xz1, xz1, xz1};

      // 24 independent MFMAs; per-step scalars ride in as C operands
      floatx4 a0[3][4], a1[3][4];
#pragma unroll
      for (int g = 0; g < 3; ++g) {
#pragma unroll
        for (int kt = 0; kt < 4; ++kt) {
          floatx4 c0 = (kt == 0) ? ((g == 0) ? cR0 : (g == 1) ? cZ0 : cNbv[0]) : z4;
          a0[g][kt] = __builtin_amdgcn_mfma_f32_16x16x32_f16(haf[kt], whf[0][g][kt], c0, 0, 0, 0);
        }
      }
#pragma unroll
      for (int g = 0; g < 3; ++g) {
#pragma unroll
        for (int kt = 0; kt < 4; ++kt) {
          floatx4 c1 = (kt == 0) ? ((g == 0) ? cR1 : (g == 1) ? cZ1 : cNbv[1]) : z4;
          a1[g][kt] = __builtin_amdgcn_mfma_f32_16x16x32_f16(haf[kt], whf[1][g][kt], c1, 0, 0, 0);
        }
      }

      // gates for col-tile 0 (valid in every lane: all A-rows identical)
      {
        float ar = (a0[0][0][0] + a0[0][1][0]) + (a0[0][2][0] + a0[0][3][0]);
        float rr = __builtin_amdgcn_rcpf(1.f + __builtin_amdgcn_exp2f(-ar));
        float az = (a0[1][0][0] + a0[1][1][0]) + (a0[1][2][0] + a0[1][3][0]);
        float zz = __builtin_amdgcn_rcpf(1.f + __builtin_amdgcn_exp2f(-az));
        float an = (a0[2][0][0] + a0[2][1][0]) + (a0[2][2][0] + a0[2][3][0]);
        float yn = fmaf(rr, an, xn0);
        float t  = __builtin_amdgcn_exp2f(-fmaxf(yn, -80.f));
        float nn = fmaf(2.f, __builtin_amdgcn_rcpf(1.f + t), -1.f);
        hold0 = fmaf(zz, hold0 - nn, nn);
      }
      // gates for col-tile 1
      {
        float ar = (a1[0][0][0] + a1[0][1][0]) + (a1[0][2][0] + a1[0][3][0]);
        float rr = __builtin_amdgcn_rcpf(1.f + __builtin_amdgcn_exp2f(-ar));
        float az = (a1[1][0][0] + a1[1][1][0]) + (a1[1][2][0] + a1[1][3][0]);
        float zz = __builtin_amdgcn_rcpf(1.f + __builtin_amdgcn_exp2f(-az));
        float an = (a1[2][0][0] + a1[2][1][0]) + (a1[2][2][0] + a1[2][3][0]);
        float yn = fmaf(rr, an, xn1);
        float t  = __builtin_amdgcn_exp2f(-fmaxf(yn, -80.f));
        float nn = fmaf(2.f, __builtin_amdgcn_rcpf(1.f + t), -1.f);
        hold1 = fmaf(zz, hold1 - nn, nn);
      }

      if (quad == 0) {
        hist[s + 1][j0] = (_Float16)hold0;
        hist[s + 1][j1] = (_Float16)hold1;
      }
      LGKM_BARRIER();
      xv0 = xvn0;
      xv1 = xvn1;
    }

    // ---- fused FC for this chunk (waves 0..1); wave 2 carries h ----
    if (wv < 2) {
      floatx4 fa = z4;
#pragma unroll
      for (int kt = 0; kt < 4; ++kt) {
        half8 af = *(const half8*)&hist[1 + wv * 16 + col][kt * 32 + quad * 8];
        fa = __builtin_amdgcn_mfma_f32_16x16x32_f16(af, fcf[kt], fa, 0, 0, 0);
      }
      if (col < K_CLS) {
#pragma unroll
        for (int i = 0; i < 4; ++i) {
          int t  = c * CHUNK + wv * 16 + quad * 4 + i;
          int tt = dir ? (T_LEN - 1 - t) : t;
          atomicAdd(out + ((size_t)b * T_LEN + tt) * K_CLS + col, fa[i]);
        }
      }
    } else if (wv == 2) {
      // carry h into row 0 for the next chunk (ordered by next chunk's barriers)
      ((unsigned int*)&hist[0][0])[lane] = ((const unsigned int*)&hist[CHUNK][0])[lane];
    }
  }
}

extern "C" void kernel_launch(void* const* d_in, const int* in_sizes, int n_in,
                              void* d_out, int out_size, void* d_ws, size_t ws_size,
                              hipStream_t stream) {
  (void)in_sizes; (void)n_in; (void)d_ws; (void)ws_size; (void)out_size;
  const float* x     = (const float*)d_in[0];
  const float* Wih_f = (const float*)d_in[1];
  const float* Whh_f = (const float*)d_in[2];
  const float* bih_f = (const float*)d_in[3];
  const float* bhh_f = (const float*)d_in[4];
  const float* Wih_b = (const float*)d_in[5];
  const float* Whh_b = (const float*)d_in[6];
  const float* bih_b = (const float*)d_in[7];
  const float* bhh_b = (const float*)d_in[8];
  const float* Wfc   = (const float*)d_in[9];
  const float* bfc   = (const float*)d_in[10];
  float* out = (float*)d_out;

  const int n_out = B_SZ * T_LEN * K_CLS;
  init_out_kernel<<<(n_out + 255) / 256, 256, 0, stream>>>(out, bfc);
  gru_bidir_kernel<<<B_SZ * 2, 256, 0, stream>>>(x, Wih_f, Whh_f, bih_f, bhh_f,
                                                 Wih_b, Whh_b, bih_b, bhh_b, Wfc, out);
}

// Round 5
// 1981.345 us; speedup vs baseline: 1.0098x; 1.0098x over previous
//
#include <hip/hip_runtime.h>
#include <cstdint>
#include <cstddef>

#define T_LEN   4096
#define B_SZ    32
#define H_DIM   128
#define DX      128
#define K_CLS   10
#define CHUNK   32
#define NCHUNKS (T_LEN / CHUNK)
#define XA_LD   136    // f16 per xA row
#define XPP_LD  1040   // f16 per xPP pair-row: 128 units * 8 + 16 pad
#define HI_LD   136

typedef _Float16 half2v  __attribute__((ext_vector_type(2)));
typedef _Float16 half4   __attribute__((ext_vector_type(4)));
typedef _Float16 half8   __attribute__((ext_vector_type(8)));
typedef float    floatx4 __attribute__((ext_vector_type(4)));
typedef unsigned int uint4v __attribute__((ext_vector_type(4)));

// Raw barrier: orders LDS ops only (no vmcnt drain).
#define LGKM_BARRIER() do {                                   \
    asm volatile("s_waitcnt lgkmcnt(0)" ::: "memory");        \
    __builtin_amdgcn_s_barrier();                             \
    asm volatile("" ::: "memory");                            \
  } while (0)

// quad_perm broadcast: every lane of each consecutive-4 group gets lane p's value.
#define QB(v, C) ((unsigned)__builtin_amdgcn_update_dpp((int)(v), (int)(v), (C), 0xF, 0xF, false))

__global__ void __launch_bounds__(256) init_out_kernel(float* __restrict__ out,
                                                       const float* __restrict__ bfc) {
  int i = blockIdx.x * 256 + threadIdx.x;
  if (i < B_SZ * T_LEN * K_CLS) out[i] = bfc[i % K_CLS];
}

// One block per (batch, direction) scan. 8 waves (512 threads, 2/SIMD):
//  - hp = Whh @ h via MFMA, all A-rows = broadcast h; each wave owns 16 units
//  - h fragment: ONE ds_read_b128 per lane (kt = col&3) + DPP quad_perm
//    broadcasts build the other 3 kt fragments in-register (LDS ops 4->1/wave)
//  - xp packed in step-PAIRS [pair][j*8]: one b128 read per 2 steps
//  - weights pre-scaled by log2e (r,z) / 2log2e (n) -> raw v_exp2 gates
//  - raw lgkm-only barriers in the scan (no vmcnt drains on the critical path)
__global__ void __launch_bounds__(512, 2)
gru_bidir_kernel(const float* __restrict__ x,
                 const float* __restrict__ Wih_f, const float* __restrict__ Whh_f,
                 const float* __restrict__ bih_f, const float* __restrict__ bhh_f,
                 const float* __restrict__ Wih_b, const float* __restrict__ Whh_b,
                 const float* __restrict__ bih_b, const float* __restrict__ bhh_b,
                 const float* __restrict__ Wfc, float* __restrict__ out) {
  const int tid = threadIdx.x;
  const int bid = blockIdx.x;
  const int b   = bid & (B_SZ - 1);
  const int dir = bid >> 5;

  const float* Wih = dir ? Wih_b : Wih_f;
  const float* Whh = dir ? Whh_b : Whh_f;
  const float* bih = dir ? bih_b : bih_f;
  const float* bhh = dir ? bhh_b : bhh_f;

  const int lane = tid & 63;
  const int wv   = tid >> 6;      // 0..7
  const int col  = lane & 15;
  const int quad = lane >> 4;
  const int jloc = wv * 16 + col; // this lane's hidden unit

  __shared__ __align__(16) _Float16 xA[CHUNK][XA_LD];
  __shared__ __align__(16) _Float16 xPP[CHUNK / 2][XPP_LD]; // [pair][j*8 + sub*4 + g]
  __shared__ __align__(16) _Float16 hist[CHUNK + 1][HI_LD];

  const float LOG2E = 1.44269504f;

  // ---- stationary weight fragments, pre-scaled for exp2-native gates ----
  half8 whf[3][4];
  half8 wif[3][4];
#pragma unroll
  for (int g = 0; g < 3; ++g) {
    const float gs = (g == 2) ? 2.0f * LOG2E : LOG2E;
#pragma unroll
    for (int kt = 0; kt < 4; ++kt) {
      const float* sh = Whh + (size_t)(g * H_DIM + jloc) * H_DIM + kt * 32 + quad * 8;
      const float* si = Wih + (size_t)(g * H_DIM + jloc) * DX + kt * 32 + quad * 8;
      half8 vh, vi;
#pragma unroll
      for (int e = 0; e < 8; ++e) {
        vh[e] = (_Float16)(sh[e] * gs);
        vi[e] = (_Float16)(si[e] * gs);
      }
      whf[g][kt] = vh;
      wif[g][kt] = vi;
    }
  }
  const float bias_r = (bih[jloc] + bhh[jloc]) * LOG2E;
  const float bias_z = (bih[H_DIM + jloc] + bhh[H_DIM + jloc]) * LOG2E;
  const float bias_n = bih[2 * H_DIM + jloc] * (2.0f * LOG2E);
  const float bhn_s  = bhh[2 * H_DIM + jloc] * (2.0f * LOG2E);
  const floatx4 cNb  = {bhn_s, bhn_s, bhn_s, bhn_s};

  // ---- Wfc fragments for fused FC (waves 0..1) ----
  half8 fcf[4];
  if (wv < 2) {
#pragma unroll
    for (int kt = 0; kt < 4; ++kt) {
      half8 v;
#pragma unroll
      for (int e = 0; e < 8; ++e) {
        int k = kt * 32 + quad * 8 + e;
        v[e] = (col < K_CLS) ? (_Float16)Wfc[(size_t)col * (2 * H_DIM) + dir * H_DIM + k]
                             : (_Float16)0.f;
      }
      fcf[kt] = v;
    }
  }

  if (tid < H_DIM) hist[0][tid] = (_Float16)0.f;

  // ---- x prefetch: thread covers row s_row, 8 consecutive floats ----
  const int s_row = tid >> 4;
  const int cb    = (tid & 15) * 8;
  float4 px0, px1;
  {
    int t0 = dir ? (T_LEN - 1 - s_row) : s_row;
    const float* xr = x + ((size_t)b * T_LEN + t0) * DX + cb;
    px0 = *(const float4*)xr;
    px1 = *(const float4*)(xr + 4);
  }

  float hold = 0.f;  // carried h for unit jloc (all quads redundant)
  const floatx4 z4 = {0.f, 0.f, 0.f, 0.f};
  const int myoff = (col & 3) * 32 + quad * 8;  // this lane's h-fragment offset
  __syncthreads();

  for (int c = 0; c < NCHUNKS; ++c) {
    // ---- stage x chunk into LDS (f16) ----
    {
      half8 v;
      v[0] = (_Float16)px0.x; v[1] = (_Float16)px0.y; v[2] = (_Float16)px0.z; v[3] = (_Float16)px0.w;
      v[4] = (_Float16)px1.x; v[5] = (_Float16)px1.y; v[6] = (_Float16)px1.z; v[7] = (_Float16)px1.w;
      *(half8*)&xA[s_row][cb] = v;
    }
    LGKM_BARRIER();

    // ---- xp = (x @ Wih^T + bias), pre-scaled, packed in step-pairs ----
#pragma unroll
    for (int mt = 0; mt < 2; ++mt) {
      half8 af[4];
#pragma unroll
      for (int kt = 0; kt < 4; ++kt)
        af[kt] = *(const half8*)&xA[mt * 16 + col][kt * 32 + quad * 8];
      floatx4 pr = z4, pz = z4, pn = z4;
#pragma unroll
      for (int kt = 0; kt < 4; ++kt) {
        pr = __builtin_amdgcn_mfma_f32_16x16x32_f16(af[kt], wif[0][kt], pr, 0, 0, 0);
        pz = __builtin_amdgcn_mfma_f32_16x16x32_f16(af[kt], wif[1][kt], pz, 0, 0, 0);
        pn = __builtin_amdgcn_mfma_f32_16x16x32_f16(af[kt], wif[2][kt], pn, 0, 0, 0);
      }
#pragma unroll
      for (int i = 0; i < 4; ++i) {
        int row = mt * 16 + quad * 4 + i;
        half4 w;
        w[0] = (_Float16)(pr[i] + bias_r);
        w[1] = (_Float16)(pz[i] + bias_z);
        w[2] = (_Float16)(pn[i] + bias_n);
        w[3] = (_Float16)0.f;
        *(half4*)&xPP[row >> 1][jloc * 8 + (row & 1) * 4] = w;
      }
    }

    // prefetch next chunk's x (stays in flight across the scan)
    if (c + 1 < NCHUNKS) {
      int s  = (c + 1) * CHUNK + s_row;
      int t0 = dir ? (T_LEN - 1 - s) : s;
      const float* xr = x + ((size_t)b * T_LEN + t0) * DX + cb;
      px0 = *(const float4*)xr;
      px1 = *(const float4*)(xr + 4);
    }
    LGKM_BARRIER();

    half8 xq  = *(const half8*)&xPP[0][jloc * 8];  // pair 0 (steps 0,1)
    half8 xqn = xq;

    // ---- sequential scan (fully unrolled: immediate LDS offsets) ----
#pragma unroll
    for (int s = 0; s < CHUNK; ++s) {
      // ONE b128 per lane: fragment kt = col&3; DPP builds the rest
      uint4v ou = __builtin_bit_cast(uint4v, *(const half8*)&hist[s][myoff]);
      if (((s & 1) == 0) && s < CHUNK - 2)
        xqn = *(const half8*)&xPP[(s >> 1) + 1][jloc * 8];  // next pair

      uint4v h0u, h1u, h2u, h3u;
      h0u.x = QB(ou.x, 0x00); h0u.y = QB(ou.y, 0x00); h0u.z = QB(ou.z, 0x00); h0u.w = QB(ou.w, 0x00);
      h1u.x = QB(ou.x, 0x55); h1u.y = QB(ou.y, 0x55); h1u.z = QB(ou.z, 0x55); h1u.w = QB(ou.w, 0x55);
      h2u.x = QB(ou.x, 0xAA); h2u.y = QB(ou.y, 0xAA); h2u.z = QB(ou.z, 0xAA); h2u.w = QB(ou.w, 0xAA);
      h3u.x = QB(ou.x, 0xFF); h3u.y = QB(ou.y, 0xFF); h3u.z = QB(ou.z, 0xFF); h3u.w = QB(ou.w, 0xFF);
      half8 haf0 = __builtin_bit_cast(half8, h0u);
      half8 haf1 = __builtin_bit_cast(half8, h1u);
      half8 haf2 = __builtin_bit_cast(half8, h2u);
      half8 haf3 = __builtin_bit_cast(half8, h3u);

      const int sub = (s & 1) * 4;
      float xrf = (float)xq[sub + 0];
      float xzf = (float)xq[sub + 1];
      float xnf = (float)xq[sub + 2];
      floatx4 cR = {xrf, xrf, xrf, xrf};
      floatx4 cZ = {xzf, xzf, xzf, xzf};

      // 12 independent MFMAs; per-step scalars ride in as C operands
      floatx4 cr0 = __builtin_amdgcn_mfma_f32_16x16x32_f16(haf0, whf[0][0], cR, 0, 0, 0);
      floatx4 cr1 = __builtin_amdgcn_mfma_f32_16x16x32_f16(haf1, whf[0][1], z4, 0, 0, 0);
      floatx4 cr2 = __builtin_amdgcn_mfma_f32_16x16x32_f16(haf2, whf[0][2], z4, 0, 0, 0);
      floatx4 cr3 = __builtin_amdgcn_mfma_f32_16x16x32_f16(haf3, whf[0][3], z4, 0, 0, 0);
      floatx4 cz0 = __builtin_amdgcn_mfma_f32_16x16x32_f16(haf0, whf[1][0], cZ, 0, 0, 0);
      floatx4 cz1 = __builtin_amdgcn_mfma_f32_16x16x32_f16(haf1, whf[1][1], z4, 0, 0, 0);
      floatx4 cz2 = __builtin_amdgcn_mfma_f32_16x16x32_f16(haf2, whf[1][2], z4, 0, 0, 0);
      floatx4 cz3 = __builtin_amdgcn_mfma_f32_16x16x32_f16(haf3, whf[1][3], z4, 0, 0, 0);
      floatx4 cn0 = __builtin_amdgcn_mfma_f32_16x16x32_f16(haf0, whf[2][0], cNb, 0, 0, 0);
      floatx4 cn1 = __builtin_amdgcn_mfma_f32_16x16x32_f16(haf1, whf[2][1], z4, 0, 0, 0);
      floatx4 cn2 = __builtin_amdgcn_mfma_f32_16x16x32_f16(haf2, whf[2][2], z4, 0, 0, 0);
      floatx4 cn3 = __builtin_amdgcn_mfma_f32_16x16x32_f16(haf3, whf[2][3], z4, 0, 0, 0);

      // valid in EVERY lane (all A-rows identical)
      float ar  = (cr0[0] + cr1[0]) + (cr2[0] + cr3[0]);
      float rr  = __builtin_amdgcn_rcpf(1.f + __builtin_amdgcn_exp2f(-ar));
      float az  = (cz0[0] + cz1[0]) + (cz2[0] + cz3[0]);
      float zz  = __builtin_amdgcn_rcpf(1.f + __builtin_amdgcn_exp2f(-az));
      float anb = (cn0[0] + cn1[0]) + (cn2[0] + cn3[0]);
      float yn  = fmaf(rr, anb, xnf);
      float t   = __builtin_amdgcn_exp2f(-fmaxf(yn, -80.f));
      float nn  = fmaf(2.f, __builtin_amdgcn_rcpf(1.f + t), -1.f);
      hold = fmaf(zz, hold - nn, nn);

      if (quad == 0) hist[s + 1][jloc] = (_Float16)hold;
      LGKM_BARRIER();
      if (s & 1) xq = xqn;
    }

    // ---- fused FC for this chunk (waves 0..1) ----
    if (wv < 2) {
      floatx4 fa = z4;
#pragma unroll
      for (int kt = 0; kt < 4; ++kt) {
        half8 af = *(const half8*)&hist[1 + wv * 16 + col][kt * 32 + quad * 8];
        fa = __builtin_amdgcn_mfma_f32_16x16x32_f16(af, fcf[kt], fa, 0, 0, 0);
      }
      if (col < K_CLS) {
#pragma unroll
        for (int i = 0; i < 4; ++i) {
          int t  = c * CHUNK + wv * 16 + quad * 4 + i;
          int tt = dir ? (T_LEN - 1 - t) : t;
          atomicAdd(out + ((size_t)b * T_LEN + tt) * K_CLS + col, fa[i]);
        }
      }
    }
    // carry h into row 0 for the next chunk (ordered by next chunk's barriers)
    if (tid >= 256 && tid < 256 + H_DIM) hist[0][tid - 256] = hist[CHUNK][tid - 256];
  }
}

extern "C" void kernel_launch(void* const* d_in, const int* in_sizes, int n_in,
                              void* d_out, int out_size, void* d_ws, size_t ws_size,
                              hipStream_t stream) {
  (void)in_sizes; (void)n_in; (void)d_ws; (void)ws_size; (void)out_size;
  const float* x     = (const float*)d_in[0];
  const float* Wih_f = (const float*)d_in[1];
  const float* Whh_f = (const float*)d_in[2];
  const float* bih_f = (const float*)d_in[3];
  const float* bhh_f = (const float*)d_in[4];
  const float* Wih_b = (const float*)d_in[5];
  const float* Whh_b = (const float*)d_in[6];
  const float* bih_b = (const float*)d_in[7];
  const float* bhh_b = (const float*)d_in[8];
  const float* Wfc   = (const float*)d_in[9];
  const float* bfc   = (const float*)d_in[10];
  float* out = (float*)d_out;

  const int n_out = B_SZ * T_LEN * K_CLS;
  init_out_kernel<<<(n_out + 255) / 256, 256, 0, stream>>>(out, bfc);
  gru_bidir_kernel<<<B_SZ * 2, 512, 0, stream>>>(x, Wih_f, Whh_f, bih_f, bhh_f,
                                                 Wih_b, Whh_b, bih_b, bhh_b, Wfc, out);
}